// Round 1
// baseline (755.700 us; speedup 1.0000x reference)
//
#include <hip/hip_runtime.h>

// ---------------- types / helpers ----------------
typedef __attribute__((ext_vector_type(4))) float f32x4;
typedef __attribute__((ext_vector_type(8))) short s16x8;

#define MFMA16(a, b, c) __builtin_amdgcn_mfma_f32_16x16x32_bf16(a, b, c, 0, 0, 0)

static __device__ __forceinline__ unsigned short f2b(float f) {
  unsigned int u = __float_as_uint(f);
  u += 0x7fff + ((u >> 16) & 1);   // round-to-nearest-even
  return (unsigned short)(u >> 16);
}

static __device__ __forceinline__ void gload_lds16(const unsigned short* g, unsigned short* l) {
  __builtin_amdgcn_global_load_lds(
      (const __attribute__((address_space(1))) unsigned int*)g,
      (__attribute__((address_space(3))) unsigned int*)l, 16, 0, 0);
}

// ---------------- problem constants ----------------
#define BW    2048
#define NTOK  49
#define CDIM  384
#define NHEAD 12
#define HDIM  32
#define NWIN  64
#define MROWS (BW * NTOK)        // 100352
#define SCALE 0.17677669529663687f  // 32^-0.5

// workspace byte offsets
#define OFF_X    ((size_t)0)                 // x bf16 / attn_out bf16 (77,070,336 B)
#define OFF_QKV  ((size_t)77070336)          // qkv bf16 (231,211,008 B)
#define OFF_QW   ((size_t)308281344)         // qkv_w bf16 (884,736 B)
#define OFF_PW   ((size_t)309166080)         // proj_w bf16 (294,912 B)
#define OFF_COMB ((size_t)309460992)         // comb f32 (7,375,872 B)

// ---------------- cast fp32 -> bf16 (x4 vectorized) ----------------
__global__ __launch_bounds__(256) void cast_kernel(const float* __restrict__ src,
                                                   unsigned short* __restrict__ dst, int n4) {
  int i = blockIdx.x * 256 + threadIdx.x;
  if (i >= n4) return;
  float4 f = ((const float4*)src)[i];
  ushort4 o;
  o.x = f2b(f.x); o.y = f2b(f.y); o.z = f2b(f.z); o.w = f2b(f.w);
  ((ushort4*)dst)[i] = o;
}

// ---------------- comb[w][h][i*49+j] = mask[w][ij] + bias_table[rel(i,j)][h] ----------------
__global__ __launch_bounds__(256) void build_comb(const float* __restrict__ mask,
                                                  const float* __restrict__ bias_table,
                                                  float* __restrict__ comb) {
  int idx = blockIdx.x * 256 + threadIdx.x;
  if (idx >= NWIN * NHEAD * NTOK * NTOK) return;
  int ij = idx % (NTOK * NTOK);
  int wh = idx / (NTOK * NTOK);
  int h = wh % NHEAD;
  int w = wh / NHEAD;
  int i = ij / NTOK, j = ij % NTOK;
  int yi = i / 7, xi = i % 7, yj = j / 7, xj = j % 7;
  int rel = (yi - yj + 6) * 13 + (xi - xj + 6);
  comb[idx] = mask[w * (NTOK * NTOK) + ij] + bias_table[rel * NHEAD + h];
}

// ---------------- m97-style GEMM: C[M,N] = A[M,K] * Bt[N,K]^T + bias ----------------
// 128x128 tile, BK=32, 256 threads (4 waves, each 64x64), 16x16x32 bf16 MFMA.
// M%128==0, N%128? (N=1152:yes, N=384: 3 tiles of 128: yes), K%32==0 — no bounds checks.
template <bool OUT_BF16>
__global__ __launch_bounds__(256) void gemm_bt(const unsigned short* __restrict__ A,
                                               const unsigned short* __restrict__ Bt,
                                               const float* __restrict__ bias,
                                               void* __restrict__ Cv,
                                               int M, int N, int K) {
  __shared__ __align__(16) unsigned short As[128 * 32];
  __shared__ __align__(16) unsigned short Bs[128 * 32];
  const int tid = threadIdx.x;
  const int lane = tid & 63;
  const int wave = tid >> 6;
  const int lr = lane & 15, lg = lane >> 4;
  const int wm = (wave >> 1) * 64, wn = (wave & 1) * 64;
  const size_t tileM = (size_t)blockIdx.y * 128;
  const size_t tileN = (size_t)blockIdx.x * 128;

  const unsigned short* Ab = A + tileM * K;
  const unsigned short* Bb = Bt + tileN * K;

  // staging: chunk c covers 8 bf16; row = c>>2, kcol = (c&3)*8; LDS dst = c*16B (wave-uniform + lane*16)
  const int c0 = tid, c1 = tid + 256;
  const size_t a0 = (size_t)(c0 >> 2) * K + (c0 & 3) * 8;
  const size_t a1 = (size_t)(c1 >> 2) * K + (c1 & 3) * 8;

  f32x4 acc[4][4] = {};

  for (int k0 = 0; k0 < K; k0 += 32) {
    gload_lds16(Ab + a0 + k0, As + c0 * 8);
    gload_lds16(Ab + a1 + k0, As + c1 * 8);
    gload_lds16(Bb + a0 + k0, Bs + c0 * 8);
    gload_lds16(Bb + a1 + k0, Bs + c1 * 8);
    __syncthreads();   // compiler emits vmcnt(0) drain -> LDS ready
    s16x8 af[4], bf[4];
#pragma unroll
    for (int mt = 0; mt < 4; ++mt)
      af[mt] = *(const s16x8*)&As[(wm + mt * 16 + lr) * 32 + lg * 8];
#pragma unroll
    for (int nt = 0; nt < 4; ++nt)
      bf[nt] = *(const s16x8*)&Bs[(wn + nt * 16 + lr) * 32 + lg * 8];
#pragma unroll
    for (int mt = 0; mt < 4; ++mt)
#pragma unroll
      for (int nt = 0; nt < 4; ++nt)
        acc[mt][nt] = MFMA16(af[mt], bf[nt], acc[mt][nt]);
    __syncthreads();   // protect LDS from next-iter overwrite
  }

  unsigned short* Cb = (unsigned short*)Cv;
  float* Cf = (float*)Cv;
#pragma unroll
  for (int nt = 0; nt < 4; ++nt) {
    const size_t gcol = tileN + wn + nt * 16 + lr;
    const float bv = bias[gcol];
#pragma unroll
    for (int mt = 0; mt < 4; ++mt)
#pragma unroll
      for (int r = 0; r < 4; ++r) {
        const size_t grow = tileM + wm + mt * 16 + lg * 4 + r;  // C/D: row=(lane>>4)*4+r, col=lane&15
        const float v = acc[mt][nt][r] + bv;
        if (OUT_BF16) Cb[grow * (size_t)N + gcol] = f2b(v);
        else          Cf[grow * (size_t)N + gcol] = v;
      }
  }
}

// ---------------- attention: one wave per (window, head) ----------------
// qkv: [BW*49, 1152] bf16 (col = which*384 + h*32 + d)
// comb: [64][12][49*49] f32 ; out: [BW*49, 384] bf16
#define PSTR 72   // LDS row stride (elements): 144B rows, 16B-aligned, bank-spread
__global__ __launch_bounds__(64) void attn_kernel(const unsigned short* __restrict__ qkv,
                                                  const float* __restrict__ comb,
                                                  unsigned short* __restrict__ out) {
  __shared__ __align__(16) unsigned short Pt[64 * PSTR];
  __shared__ __align__(16) unsigned short VT[32 * PSTR];
  const int b = blockIdx.x;
  const int h = blockIdx.y;
  const int lane = threadIdx.x;
  const int lr = lane & 15, lg = lane >> 4;
  const unsigned short* base = qkv + (size_t)b * NTOK * (3 * CDIM) + h * HDIM;

  // zero VT (cols k>=49 must be 0.0 for PV; garbage LDS could be NaN)
  for (int i = lane; i < (32 * PSTR) / 8; i += 64) {
    s16x8 z;
#pragma unroll
    for (int j = 0; j < 8; ++j) z[j] = 0;
    *(s16x8*)&VT[i * 8] = z;
  }
  __syncthreads();

  // stage V transposed: VT[d][k] = V[k][d]; consecutive lanes -> consecutive k (2-way banks)
  for (int c = lane; c < NTOK * 4; c += 64) {
    int k = c % NTOK;
    int dg = c / NTOK;
    s16x8 v = *(const s16x8*)(base + 2 * CDIM + (size_t)k * (3 * CDIM) + dg * 8);
#pragma unroll
    for (int j = 0; j < 8; ++j) VT[(dg * 8 + j) * PSTR + k] = v[j];
  }

  // Q,K fragments straight from global: A[m=lr][k=lg*8+j], B(K^T)[n=lr][k=lg*8+j]
  s16x8 qf[4], kf[4];
#pragma unroll
  for (int mt = 0; mt < 4; ++mt) {
    int t = mt * 16 + lr;
    if (t < NTOK) {
      qf[mt] = *(const s16x8*)(base + (size_t)t * (3 * CDIM) + lg * 8);
      kf[mt] = *(const s16x8*)(base + CDIM + (size_t)t * (3 * CDIM) + lg * 8);
    } else {
#pragma unroll
      for (int j = 0; j < 8; ++j) { qf[mt][j] = 0; kf[mt][j] = 0; }
    }
  }

  f32x4 S[4][4] = {};
#pragma unroll
  for (int mt = 0; mt < 4; ++mt)
#pragma unroll
    for (int nt = 0; nt < 4; ++nt)
      S[mt][nt] = MFMA16(qf[mt], kf[nt], S[mt][nt]);

  const float* cb = comb + ((size_t)(b & 63) * NHEAD + h) * (NTOK * NTOK);

  // masked softmax per row; rows live across 16 lanes sharing lg, 4 regs (nt)
#pragma unroll
  for (int mt = 0; mt < 4; ++mt) {
#pragma unroll
    for (int r = 0; r < 4; ++r) {
      const int row = mt * 16 + lg * 4 + r;
      const bool rowok = row < NTOK;
      float sv[4];
      float mx = -1e30f;
#pragma unroll
      for (int nt = 0; nt < 4; ++nt) {
        const int col = nt * 16 + lr;
        float s;
        if (col < NTOK)
          s = rowok ? S[mt][nt][r] * SCALE + cb[row * NTOK + col] : 0.0f;
        else
          s = -1e30f;
        sv[nt] = s;
        mx = fmaxf(mx, s);
      }
#pragma unroll
      for (int off = 8; off; off >>= 1) mx = fmaxf(mx, __shfl_xor(mx, off, 16));
      float sum = 0.f;
#pragma unroll
      for (int nt = 0; nt < 4; ++nt) {
        float e = exp2f((sv[nt] - mx) * 1.4426950408889634f);
        sv[nt] = e;
        sum += e;
      }
#pragma unroll
      for (int off = 8; off; off >>= 1) sum += __shfl_xor(sum, off, 16);
      const float inv = 1.0f / sum;
#pragma unroll
      for (int nt = 0; nt < 4; ++nt)
        Pt[row * PSTR + nt * 16 + lr] = f2b(sv[nt] * inv);
    }
  }
  __syncthreads();

  // O = P(49x64pad) * V(64x32): A-frag from Pt, B-frag from VT
  f32x4 O[4][2] = {};
#pragma unroll
  for (int ks = 0; ks < 2; ++ks) {
    s16x8 pf[4], vf[2];
#pragma unroll
    for (int mt = 0; mt < 4; ++mt)
      pf[mt] = *(const s16x8*)&Pt[(mt * 16 + lr) * PSTR + ks * 32 + lg * 8];
#pragma unroll
    for (int n2 = 0; n2 < 2; ++n2)
      vf[n2] = *(const s16x8*)&VT[(n2 * 16 + lr) * PSTR + ks * 32 + lg * 8];
#pragma unroll
    for (int mt = 0; mt < 4; ++mt)
#pragma unroll
      for (int n2 = 0; n2 < 2; ++n2)
        O[mt][n2] = MFMA16(pf[mt], vf[n2], O[mt][n2]);
  }

  unsigned short* ob = out + (size_t)b * NTOK * CDIM + h * HDIM;
#pragma unroll
  for (int mt = 0; mt < 4; ++mt)
#pragma unroll
    for (int r = 0; r < 4; ++r) {
      const int row = mt * 16 + lg * 4 + r;
      if (row < NTOK) {
#pragma unroll
        for (int n2 = 0; n2 < 2; ++n2)
          ob[(size_t)row * CDIM + n2 * 16 + lr] = f2b(O[mt][n2][r]);
      }
    }
}

// ---------------- launch ----------------
extern "C" void kernel_launch(void* const* d_in, const int* in_sizes, int n_in,
                              void* d_out, int out_size, void* d_ws, size_t ws_size,
                              hipStream_t stream) {
  const float* x          = (const float*)d_in[0];
  const float* mask       = (const float*)d_in[1];
  const float* qkv_w      = (const float*)d_in[2];
  const float* qkv_b      = (const float*)d_in[3];
  const float* proj_w     = (const float*)d_in[4];
  const float* proj_b     = (const float*)d_in[5];
  const float* bias_table = (const float*)d_in[6];
  float* out = (float*)d_out;
  char* ws = (char*)d_ws;

  unsigned short* xb   = (unsigned short*)(ws + OFF_X);    // x bf16, later reused as attn_out
  unsigned short* qkvb = (unsigned short*)(ws + OFF_QKV);
  unsigned short* qw   = (unsigned short*)(ws + OFF_QW);
  unsigned short* pw   = (unsigned short*)(ws + OFF_PW);
  float* comb          = (float*)(ws + OFF_COMB);

  // casts
  cast_kernel<<<(MROWS * CDIM / 4 + 255) / 256, 256, 0, stream>>>(x, xb, MROWS * CDIM / 4);
  cast_kernel<<<(3 * CDIM * CDIM / 4 + 255) / 256, 256, 0, stream>>>(qkv_w, qw, 3 * CDIM * CDIM / 4);
  cast_kernel<<<(CDIM * CDIM / 4 + 255) / 256, 256, 0, stream>>>(proj_w, pw, CDIM * CDIM / 4);

  // combined mask+bias
  {
    int n = NWIN * NHEAD * NTOK * NTOK;
    build_comb<<<(n + 255) / 256, 256, 0, stream>>>(mask, bias_table, comb);
  }

  // qkv = x @ qkv_w^T + qkv_b   (bf16 out)
  gemm_bt<true><<<dim3((3 * CDIM) / 128, MROWS / 128), 256, 0, stream>>>(
      xb, qw, qkv_b, qkvb, MROWS, 3 * CDIM, CDIM);

  // attention (writes attn_out into xb region)
  attn_kernel<<<dim3(BW, NHEAD), 64, 0, stream>>>(qkvb, comb, xb);

  // out = attn_out @ proj_w^T + proj_b   (fp32 out)
  gemm_bt<false><<<dim3(CDIM / 128, MROWS / 128), 256, 0, stream>>>(
      xb, pw, proj_b, out, MROWS, CDIM, CDIM);
}